// Round 5
// baseline (171.694 us; speedup 1.0000x reference)
//
#include <hip/hip_runtime.h>
#include <hip/hip_bf16.h>

// Problem constants
#define BB 256
#define TT 256
#define CC 384
#define HSS 64

typedef __bf16 bf16_t;
typedef bf16_t bf16x8 __attribute__((ext_vector_type(8)));
typedef bf16_t bf16x4 __attribute__((ext_vector_type(4)));
typedef float f32x4 __attribute__((ext_vector_type(4)));

__device__ __forceinline__ f32x4 mfma16(bf16x8 a, bf16x8 b, f32x4 c) {
    return __builtin_amdgcn_mfma_f32_16x16x32_bf16(a, b, c, 0, 0, 0);
}

__device__ __forceinline__ bf16x8 cvt8(float4 a, float4 b) {
    bf16x8 r;
    r[0] = (bf16_t)a.x; r[1] = (bf16_t)a.y; r[2] = (bf16_t)a.z; r[3] = (bf16_t)a.w;
    r[4] = (bf16_t)b.x; r[5] = (bf16_t)b.y; r[6] = (bf16_t)b.z; r[7] = (bf16_t)b.w;
    return r;
}

// ---------------- Fully fused head (QKV + causal attention), workspace-free ----------------
// One block per batch (grid 256 = 1 block/CU), 1024 thr = 16 waves, wave w owns
// one query tile. r10 changes (serial-tail attack; r1-r4 showed dur_us pinned
// at ~173 by the 2x58us harness fills — this is the last kernel-side lever):
//  * biases loaded at kernel ENTRY (were on the post-Phase-A critical path:
//    a global-latency stall right before the K/V scatter).
//  * Q-transpose hoisted BEFORE the KV-visibility barrier (Pb is wave-private
//    and disjoint from Ksw/Vsw; Wsh is dead after the aliasing fence) — its
//    two LDS round-trips overlap other waves' K/V scatter instead of
//    serializing after the barrier.
//  * Phase-B chunk body restructured for ILP: all 8 independent ds_reads
//    (4 K-frags + 4 V-frags) issue at the top of each 32-key chunk, then
//    4 QK MFMAs, then exp/pack/bounce, then 4 PV MFMAs. Previously the
//    V-reads sat after the P bounce and each chunk ran its full dependency
//    chain exposed (~400cyc x 8 chunks on the longest wave).
//  * Everything else identical to r9: in-LDS W staging from f32 originals
//    (no workspace, no prep_w), single-barrier barrier-free Phase A with
//    2-deep x rotation, K/V/Pb aliased onto dead Wsh, SIMD-balanced tiles.
__global__ __attribute__((amdgpu_flat_work_group_size(1024, 1024),
                          amdgpu_waves_per_eu(4, 4)))
void head_fused(
    const float* __restrict__ x,
    const float* __restrict__ Wq, const float* __restrict__ Wk, const float* __restrict__ Wv,
    const float* __restrict__ bq, const float* __restrict__ bk, const float* __restrict__ bv,
    float* __restrict__ out) {

    // 144 KB pool. Phase A: Wsh[73728] bf16 (whole W, swizzled layout).
    // Phase B (aliased onto dead Wsh): Ksw 32 KB | Vsw 32 KB | Pb 20 KB.
    __shared__ __align__(16) unsigned char LDSpool[147456];
    bf16_t* Wsh = (bf16_t*)LDSpool;
    uint4* Ksw = (uint4*)LDSpool;                  // [2048] K [256][64] swizzled
    uint4* Vsw = (uint4*)(LDSpool + 32768);        // [2048] V^T [64][256] swizzled
    bf16_t* Pb = (bf16_t*)(LDSpool + 65536);       // 16 x 640 per-wave Q/P bounce

    int b = blockIdx.x, tid = threadIdx.x;
    int w = tid >> 6, l = tid & 63, lr = l & 15, lq = l >> 4;
    int Mt = (w < 8) ? w : 23 - w;                // SIMD-balanced causal tile map

    const float* xr = x + ((size_t)b * TT + Mt * 16 + lr) * CC;

    // bias fragments (feature = nt*16+lr) — at ENTRY, off the critical path
    float bqv[4], bkv[4], bvv[4];
#pragma unroll
    for (int nt = 0; nt < 4; nt++) {
        bqv[nt] = bq[nt * 16 + lr];
        bkv[nt] = bk[nt * 16 + lr];
        bvv[nt] = bv[nt * 16 + lr];
    }

    // ---- in-LDS W staging: 144 (m,kc,c) triples, 9 per wave ----
    // Wsh element for (n, k): kc=k>>6, c=(k&63)>>3, e=k&7 lands at
    // kc*12288 + n*64 + (c^(n&7))*8 + e  — matches Phase A's reader XOR.
#pragma unroll
    for (int j = 0; j < 9; j++) {
        int idx = w * 9 + j;                       // wave-uniform
        int m = idx / 48, rem = idx % 48;          // m: 0=Wq 1=Wk 2=Wv
        int kc = rem >> 3, c = rem & 7;
        const float* Wm = (m == 0) ? Wq : (m == 1) ? Wk : Wv;
        int k0 = kc * 64 + c * 8;
        float v[8];
#pragma unroll
        for (int e = 0; e < 8; e++)
            v[e] = Wm[(size_t)(k0 + e) * 64 + l];  // 256-B coalesced row load
        bf16x8 pk;
#pragma unroll
        for (int e = 0; e < 8; e++) pk[e] = (bf16_t)v[e];
        int n = m * 64 + l;
        *(bf16x8*)(Wsh + (size_t)kc * 12288 + (size_t)n * 64 + (c ^ (l & 7)) * 8) = pk;
    }

    // ======== Phase A: QKV GEMM, barrier-free 6-stage dataflow ========
    f32x4 acc[12];
#pragma unroll
    for (int i = 0; i < 12; i++) acc[i] = (f32x4){0.f, 0.f, 0.f, 0.f};

    float4 xa[4], xb[4];                           // 2-deep x batch rotation

#define LOAD_XB(dst, i)                                                      \
    {                                                                        \
        _Pragma("unroll")                                                    \
        for (int t = 0; t < 2; t++)                                          \
            _Pragma("unroll")                                                \
            for (int h = 0; h < 2; h++)                                      \
                dst[t * 2 + h] =                                             \
                    *(const float4*)(xr + (i) * 64 + t * 32 + lq * 8 + h * 4); \
    }

    LOAD_XB(xa, 0);
    LOAD_XB(xb, 1);

    __syncthreads();                               // single drain: W staging + x(0,1)

#pragma unroll
    for (int kc = 0; kc < 6; kc++) {
        bf16x8 af0, af1;
        if ((kc & 1) == 0) {
            af0 = cvt8(xa[0], xa[1]); af1 = cvt8(xa[2], xa[3]);
            if (kc < 4) LOAD_XB(xa, kc + 2);       // issue stage kc+2's batch
        } else {
            af0 = cvt8(xb[0], xb[1]); af1 = cvt8(xb[2], xb[3]);
            if (kc < 4) LOAD_XB(xb, kc + 2);
        }
        const bf16_t* wbase = Wsh + kc * 12288;
#pragma unroll
        for (int nt = 0; nt < 12; nt++) {
            const bf16_t* wl = wbase + (size_t)(nt * 16 + lr) * 64;
            int pc0 = lq ^ (lr & 7);
            int pc1 = (4 + lq) ^ (lr & 7);
            acc[nt] = mfma16(af0, *(const bf16x8*)(wl + pc0 * 8), acc[nt]);
            acc[nt] = mfma16(af1, *(const bf16x8*)(wl + pc1 * 8), acc[nt]);
        }
    }
#undef LOAD_XB

    __syncthreads();      // ALIASING FENCE: all waves done reading Wsh before
                          // K/V scatter + Q bounce overwrite the same LDS bytes

    bf16_t* Pw = Pb + w * 640;                  // wave-private bounce (16 x stride-40)

    // -- Q transpose via bounce (HOISTED pre-barrier; Pw disjoint from Ksw/Vsw):
    //    C-frag(d=nt*16+lr, t=lq*4+r) -> B-frag(t=lr, d=lq*8+j)
    bf16x8 qf[2];
#pragma unroll
    for (int hh = 0; hh < 2; hh++) {            // d-halves 0..31 / 32..63
#pragma unroll
        for (int u = 0; u < 2; u++) {
            int nt = 2 * hh + u;
#pragma unroll
            for (int r = 0; r < 4; r++)
                Pw[(lq * 4 + r) * 40 + u * 16 + lr] =
                    (bf16_t)(acc[nt][r] + bqv[nt]);
        }
        qf[hh] = *(const bf16x8*)(Pw + lr * 40 + lq * 8);
    }

    // ======== K and V^T: registers -> swizzled LDS (with bias) ========
    bf16_t* KswB = (bf16_t*)Ksw;
    bf16_t* VswB = (bf16_t*)Vsw;
#pragma unroll
    for (int nt = 4; nt < 8; nt++) {            // K[s][d], chunk c at c^(s&7)
        int d = (nt - 4) * 16 + lr;
#pragma unroll
        for (int r = 0; r < 4; r++) {
            int s = Mt * 16 + lq * 4 + r;
            KswB[s * 64 + ((d >> 3) ^ (s & 7)) * 8 + (d & 7)] =
                (bf16_t)(acc[nt][r] + bkv[nt - 4]);
        }
    }
#pragma unroll
    for (int nt = 8; nt < 12; nt++) {           // V^T[d][t], chunk c at (c&~7)|((c^d)&7)
        int d = (nt - 8) * 16 + lr;
        int t0 = Mt * 16 + lq * 4;
        int c = t0 >> 3;
        bf16x4 pk;
#pragma unroll
        for (int r = 0; r < 4; r++) pk[r] = (bf16_t)(acc[nt][r] + bvv[nt - 8]);
        *(bf16x4*)(VswB + d * 256 + ((c & ~7) | ((c ^ d) & 7)) * 8 + (t0 & 7)) = pk;
    }
    __syncthreads();                            // K/V visible to all waves

    // ======== Phase B: causal attention, one tile per wave ========
    const float scale2 = 0.125f * 1.4426950408889634f; // HS^-0.5 * log2(e)

    int R0 = Mt * 16;
    int tg = R0 + lr;                           // this lane's query row (C col)
    int ktm = Mt >> 1;                          // causal bound on 32-key chunks
    int sx = lr & 7;                            // K-row XOR (s&7 == lr&7 here)

    f32x4 oacc[4] = {};
    float sum = 0.f;
#pragma unroll
    for (int kt = 0; kt < 8; kt++) {
        if (kt <= ktm) {                        // wave-uniform causal skip
            // ---- issue ALL independent LDS reads for this chunk up front ----
            const uint4* kr0 = Ksw + (kt * 32 + lr) * 8;       // u=0 K row
            const uint4* kr1 = Ksw + (kt * 32 + 16 + lr) * 8;  // u=1 K row
            bf16x8 k00 = __builtin_bit_cast(bf16x8, kr0[lq ^ sx]);
            bf16x8 k01 = __builtin_bit_cast(bf16x8, kr0[(4 + lq) ^ sx]);
            bf16x8 k10 = __builtin_bit_cast(bf16x8, kr1[lq ^ sx]);
            bf16x8 k11 = __builtin_bit_cast(bf16x8, kr1[(4 + lq) ^ sx]);
            bf16x8 vf[4];
#pragma unroll
            for (int dt = 0; dt < 4; dt++) {
                int d = dt * 16 + lr;
                int cc = kt * 4 + lq;
                vf[dt] = __builtin_bit_cast(bf16x8,
                    Vsw[d * 32 + ((cc & ~7) | ((cc ^ d) & 7))]);
            }
            // ---- 4 QK MFMAs (S^T: col=t(lr), row=s(lq*4+r)) ----
            f32x4 a0 = {0.f, 0.f, 0.f, 0.f}, a1 = {0.f, 0.f, 0.f, 0.f};
            a0 = mfma16(k00, qf[0], a0);
            a0 = mfma16(k01, qf[1], a0);
            a1 = mfma16(k10, qf[0], a1);
            a1 = mfma16(k11, qf[1], a1);
            // ---- exp + pack + bounce both 16-key halves ----
            bf16x4 p0, p1;
#pragma unroll
            for (int r = 0; r < 4; r++) {
                int sg0 = kt * 32 + lq * 4 + r;
                float p = (sg0 <= tg) ? exp2f(a0[r] * scale2) : 0.f;
                sum += p;
                p0[r] = (bf16_t)p;
                int sg1 = sg0 + 16;
                float q = (sg1 <= tg) ? exp2f(a1[r] * scale2) : 0.f;
                sum += q;
                p1[r] = (bf16_t)q;
            }
            *(bf16x4*)(Pw + lr * 40 + lq * 4) = p0;
            *(bf16x4*)(Pw + lr * 40 + 16 + lq * 4) = p1;
            // P^T B-frag: row t=lr, k = s-local = lq*8+j
            bf16x8 pf = *(const bf16x8*)(Pw + lr * 40 + lq * 8);
            // ---- 4 PV MFMAs (O^T = V^T . P^T: col=t(lr), row=d-local) ----
#pragma unroll
            for (int dt = 0; dt < 4; dt++)
                oacc[dt] = mfma16(vf[dt], pf, oacc[dt]);
        }
    }

    // denominator for query t=lr: partials live in lanes {lr,+16,+32,+48}
    sum += __shfl_xor(sum, 16);
    sum += __shfl_xor(sum, 32);
    float inv = 1.0f / sum;

    // epilogue: O^T frag -> coalesced float4 stores (d = dt*16+lq*4..+3)
    float* orow = out + ((size_t)b * TT + R0 + lr) * HSS;
#pragma unroll
    for (int dt = 0; dt < 4; dt++) {
        float4 o;
        o.x = oacc[dt][0] * inv;
        o.y = oacc[dt][1] * inv;
        o.z = oacc[dt][2] * inv;
        o.w = oacc[dt][3] * inv;
        *(float4*)(orow + dt * 16 + lq * 4) = o;
    }
}

extern "C" void kernel_launch(void* const* d_in, const int* in_sizes, int n_in,
                              void* d_out, int out_size, void* d_ws, size_t ws_size,
                              hipStream_t stream) {
    const float* x  = (const float*)d_in[0];
    const float* Wq = (const float*)d_in[1];
    const float* bq = (const float*)d_in[2];
    const float* Wk = (const float*)d_in[3];
    const float* bk = (const float*)d_in[4];
    const float* Wv = (const float*)d_in[5];
    const float* bv = (const float*)d_in[6];
    float* out = (float*)d_out;

    (void)d_ws; (void)ws_size;                 // workspace-free

    head_fused<<<BB, 1024, 0, stream>>>(x, Wq, Wk, Wv, bq, bk, bv, out);
}